// Round 4
// baseline (668.385 us; speedup 1.0000x reference)
//
#include <hip/hip_runtime.h>
#include <hip/hip_bf16.h>

#define B_   64
#define CIN  256
#define COUT 512
#define S_   4096
#define HID  64
#define KEXP 4

typedef float f32x4 __attribute__((ext_vector_type(4)));
typedef short bf16x8 __attribute__((ext_vector_type(8)));

static __device__ __forceinline__ unsigned short f2bf(float f) {
    union { float f; unsigned u; } c; c.f = f;
    unsigned r = c.u + 0x7FFFu + ((c.u >> 16) & 1u);
    return (unsigned short)(r >> 16);
}
static __device__ __forceinline__ float bf2f(unsigned short u) {
    union { unsigned u; float f; } c; c.u = ((unsigned)u) << 16;
    return c.f;
}

// ---------------- K_GRAM_PART: partial Gram (fp32) + partial pooled + xT bf16 ----------------
// grid = 256: b = bid&63, sc = bid>>6 (s-chunk of 1024). 512 threads (8 waves).
#define GSTR 68   // shorts per LDS row (136B)
__global__ __launch_bounds__(512, 2) void k_gram_part(const float* __restrict__ x,
                                                      float* __restrict__ part,
                                                      float* __restrict__ ppart,
                                                      unsigned short* __restrict__ xT) {
    __shared__ unsigned short lds[256 * GSTR];   // 34816 B
    int bid = blockIdx.x;
    int b = bid & 63, sc = bid >> 6;
    int t = threadIdx.x, lane = t & 63, wv = t >> 6;
    int wr = wv >> 1, wc = wv & 1;               // wave tile: rows wr*64.., cols wc*128..
    const float* xb = x + (size_t)b * CIN * S_;
    unsigned short* xTb = xT ? (xT + (size_t)b * S_ * CIN) : (unsigned short*)0;

    f32x4 acc[4][8] = {};
    float psum[8] = {0.f, 0.f, 0.f, 0.f, 0.f, 0.f, 0.f, 0.f};

    // xT extraction geometry: thread handles s_loc = t&63, cin chunk c0 = (t>>6)*32
    int s_loc = t & 63;
    int c0 = (t >> 6) * 32;

    for (int step = 0; step < 16; ++step) {
        int s0 = sc * 1024 + step * 64;
        __syncthreads();
#pragma unroll
        for (int p = 0; p < 8; ++p) {
            int i = t + p * 512;
            int row = i >> 4, f4 = i & 15;
            float4 v = *(const float4*)(xb + (size_t)row * S_ + s0 + f4 * 4);
            psum[p] += v.x + v.y + v.z + v.w;
            unsigned short u[4] = {f2bf(v.x), f2bf(v.y), f2bf(v.z), f2bf(v.w)};
            *(uint2*)&lds[row * GSTR + f4 * 4] = *(const uint2*)u;
        }
        __syncthreads();
        // ---- xT write: [s][cin] bf16, vector stores ----
        if (xTb) {
            unsigned short* dst = xTb + (size_t)(s0 + s_loc) * CIN + c0;
#pragma unroll
            for (int j8 = 0; j8 < 4; ++j8) {
                unsigned short tmp[8];
#pragma unroll
                for (int jj = 0; jj < 8; ++jj)
                    tmp[jj] = lds[(c0 + j8 * 8 + jj) * GSTR + s_loc];
                *(uint4*)(dst + j8 * 8) = *(const uint4*)tmp;
            }
        }
        // ---- Gram MFMA ----
#pragma unroll
        for (int kk = 0; kk < 2; ++kk) {
            bf16x8 bfr[8];
#pragma unroll
            for (int nf = 0; nf < 8; ++nf)
                bfr[nf] = *(const bf16x8*)&lds[(wc * 128 + nf * 16 + (lane & 15)) * GSTR + kk * 32 + (lane >> 4) * 8];
#pragma unroll
            for (int mfi = 0; mfi < 4; ++mfi) {
                bf16x8 afr = *(const bf16x8*)&lds[(wr * 64 + mfi * 16 + (lane & 15)) * GSTR + kk * 32 + (lane >> 4) * 8];
#pragma unroll
                for (int nf = 0; nf < 8; ++nf)
                    acc[mfi][nf] = __builtin_amdgcn_mfma_f32_16x16x32_bf16(afr, bfr[nf], acc[mfi][nf], 0, 0, 0);
            }
        }
    }
#pragma unroll
    for (int p = 0; p < 8; ++p) {
        float s = psum[p];
        s += __shfl_xor(s, 1); s += __shfl_xor(s, 2);
        s += __shfl_xor(s, 4); s += __shfl_xor(s, 8);
        if ((t & 15) == 0) ppart[((size_t)sc * 64 + b) * 256 + ((t + p * 512) >> 4)] = s;
    }
    float* pb = part + ((size_t)sc * 64 + b) * 65536;
#pragma unroll
    for (int mfi = 0; mfi < 4; ++mfi) {
#pragma unroll
        for (int r = 0; r < 4; ++r) {
            int row = wr * 64 + mfi * 16 + (lane >> 4) * 4 + r;
#pragma unroll
            for (int nf = 0; nf < 8; ++nf)
                pb[row * 256 + wc * 128 + nf * 16 + (lane & 15)] = acc[mfi][nf][r];
        }
    }
}

// ---------------- K_GRED: reduce 4 partials -> ghat bf16, pooled ----------------
__global__ __launch_bounds__(256) void k_gred(const float* __restrict__ part,
                                              const float* __restrict__ ppart,
                                              unsigned short* __restrict__ ghat,
                                              float* __restrict__ pooled) {
    int b = blockIdx.x, t = threadIdx.x;
    const size_t bo = (size_t)b * 65536;
    const size_t scs = (size_t)64 * 65536;
    const float inv = 1.f / S_;
    for (int it = 0; it < 64; ++it) {
        size_t i = (size_t)(it * 256 + t) * 4;
        float4 a0 = *(const float4*)(part + bo + i);
        float4 a1 = *(const float4*)(part + scs + bo + i);
        float4 a2 = *(const float4*)(part + 2 * scs + bo + i);
        float4 a3 = *(const float4*)(part + 3 * scs + bo + i);
        unsigned short u[4] = {f2bf((a0.x + a1.x + a2.x + a3.x) * inv),
                               f2bf((a0.y + a1.y + a2.y + a3.y) * inv),
                               f2bf((a0.z + a1.z + a2.z + a3.z) * inv),
                               f2bf((a0.w + a1.w + a2.w + a3.w) * inv)};
        *(uint2*)&ghat[bo + i] = *(const uint2*)u;
    }
    float p = ppart[(size_t)b * 256 + t] + ppart[(size_t)(64 + b) * 256 + t]
            + ppart[(size_t)(128 + b) * 256 + t] + ppart[(size_t)(192 + b) * 256 + t];
    pooled[b * 256 + t] = p * inv;
}

// ---------------- K2: attention weights ----------------
__global__ __launch_bounds__(64) void k_att(const float* __restrict__ pooled,
                                            const float* __restrict__ w1,
                                            const float* __restrict__ w2,
                                            const float* __restrict__ b2,
                                            float* __restrict__ att_out) {
    int b = blockIdx.x, t = threadIdx.x;
    __shared__ float pl[CIN];
    __shared__ float hl[HID];
    __shared__ float satt[KEXP];
    for (int j = t; j < CIN; j += 64) pl[j] = pooled[b * CIN + j];
    __syncthreads();
    float acc = 0.f;
    const float* w1r = w1 + t * CIN;
#pragma unroll 4
    for (int c = 0; c < CIN; c += 4) {
        float4 w = *(const float4*)(w1r + c);
        acc += w.x * pl[c] + w.y * pl[c + 1] + w.z * pl[c + 2] + w.w * pl[c + 3];
    }
    hl[t] = fmaxf(acc, 0.f);
    __syncthreads();
    if (t < KEXP) {
        float a = 0.f;
        for (int j = 0; j < HID; ++j) a += hl[j] * w2[t * HID + j];
        satt[t] = (a + b2[t]) * (1.0f / 30.0f);
    }
    __syncthreads();
    if (t == 0) {
        float m = fmaxf(fmaxf(satt[0], satt[1]), fmaxf(satt[2], satt[3]));
        float e0 = expf(satt[0] - m), e1 = expf(satt[1] - m);
        float e2 = expf(satt[2] - m), e3 = expf(satt[3] - m);
        float inv = 1.f / (e0 + e1 + e2 + e3);
        att_out[b * KEXP + 0] = e0 * inv;
        att_out[b * KEXP + 1] = e1 * inv;
        att_out[b * KEXP + 2] = e2 * inv;
        att_out[b * KEXP + 3] = e3 * inv;
    }
}

// ---------------- K2b: Wb[b] = sum_k att[b,k] conv_w[k]  (bf16 to ws) ----------------
__global__ __launch_bounds__(256) void k_wb(const float* __restrict__ conv_w,
                                            const float* __restrict__ att,
                                            unsigned short* __restrict__ wb) {
    int bid = blockIdx.x;
    int b = bid >> 5, o0 = (bid & 31) * 16;
    int t = threadIdx.x;
    int o = o0 + (t >> 4);
    int i0 = (t & 15) * 16;
    float ak[KEXP];
#pragma unroll
    for (int k = 0; k < KEXP; ++k) ak[k] = att[b * KEXP + k];
    float acc[16];
#pragma unroll
    for (int j = 0; j < 16; ++j) acc[j] = 0.f;
#pragma unroll
    for (int k = 0; k < KEXP; ++k) {
        const float* src = conv_w + ((size_t)(k * COUT + o)) * CIN + i0;
#pragma unroll
        for (int j4 = 0; j4 < 4; ++j4) {
            float4 v = *(const float4*)(src + j4 * 4);
            acc[j4 * 4 + 0] += ak[k] * v.x;
            acc[j4 * 4 + 1] += ak[k] * v.y;
            acc[j4 * 4 + 2] += ak[k] * v.z;
            acc[j4 * 4 + 3] += ak[k] * v.w;
        }
    }
    unsigned short us[16];
#pragma unroll
    for (int j = 0; j < 16; ++j) us[j] = f2bf(acc[j]);
    unsigned short* dst = wb + (size_t)(b * COUT + o) * CIN + i0;
    *(uint4*)(dst) = *(const uint4*)(us);
    *(uint4*)(dst + 8) = *(const uint4*)(us + 8);
}

#define ASTR 264

// ---------------- K_Z: Z[b] = Wb[b] @ Ghat[b] ----------------
__global__ __launch_bounds__(256, 2) void k_z(const unsigned short* __restrict__ wb,
                                              const unsigned short* __restrict__ ghat,
                                              float* __restrict__ zout) {
    __shared__ unsigned short lds_a[128 * ASTR];
    int bid = blockIdx.x;
    int b = bid & 63;
    int tile = bid >> 6;               // 0..7
    int m0 = (tile & 3) * 128, n0 = (tile >> 2) * 128;
    int t = threadIdx.x;
    {
        int row = t >> 1, half = t & 1;
        const unsigned short* src = wb + (size_t)(b * COUT + m0 + row) * CIN + half * 128;
        unsigned short* dstrow = &lds_a[row * ASTR + half * 128];
#pragma unroll
        for (int j = 0; j < 16; ++j)
            *(uint4*)(dstrow + j * 8) = *(const uint4*)(src + j * 8);
    }
    __syncthreads();

    int lane = t & 63;
    int wid = t >> 6;
    int arow = lane & 15;
    int kq = lane >> 4;
    int col0 = n0 + wid * 32 + (lane & 15);
    int col1 = col0 + 16;
    const unsigned short* gb = ghat + (size_t)b * 256 * 256;

    f32x4 acc[8][2] = {};
#pragma unroll
    for (int kk = 0; kk < 8; ++kk) {
        bf16x8 b0 = *(const bf16x8*)(gb + (size_t)col0 * 256 + kk * 32 + kq * 8);
        bf16x8 b1 = *(const bf16x8*)(gb + (size_t)col1 * 256 + kk * 32 + kq * 8);
#pragma unroll
        for (int mf = 0; mf < 8; ++mf) {
            int row = mf * 16 + arow;
            bf16x8 a = *(const bf16x8*)&lds_a[row * ASTR + kk * 32 + kq * 8];
            acc[mf][0] = __builtin_amdgcn_mfma_f32_16x16x32_bf16(a, b0, acc[mf][0], 0, 0, 0);
            acc[mf][1] = __builtin_amdgcn_mfma_f32_16x16x32_bf16(a, b1, acc[mf][1], 0, 0, 0);
        }
    }
#pragma unroll
    for (int mf = 0; mf < 8; ++mf) {
#pragma unroll
        for (int r = 0; r < 4; ++r) {
            int row = m0 + mf * 16 + (lane >> 4) * 4 + r;
            size_t rb = ((size_t)b * COUT + row) * 256;
#pragma unroll
            for (int nf = 0; nf < 2; ++nf) {
                int col = n0 + wid * 32 + nf * 16 + (lane & 15);
                zout[rb + col] = acc[mf][nf][r];
            }
        }
    }
}

// ---------------- K_V: mu/rstd per (b,o) ----------------
__global__ __launch_bounds__(256) void k_v(const float* __restrict__ z,
                                           const unsigned short* __restrict__ wb,
                                           const float* __restrict__ pooled,
                                           float* __restrict__ mu,
                                           float* __restrict__ rstd) {
    int gid = blockIdx.x * 4 + (threadIdx.x >> 6);   // b*512 + o
    int lane = threadIdx.x & 63;
    int b = gid >> 9;
    const float* zr = z + (size_t)gid * 256;
    const unsigned short* wr = wb + (size_t)gid * 256;

    float4 zv = *(const float4*)(zr + lane * 4);
    ushort4 wu = *(const ushort4*)(wr + lane * 4);
    float w0 = bf2f(wu.x), w1 = bf2f(wu.y), w2 = bf2f(wu.z), w3 = bf2f(wu.w);
    float4 pv = *(const float4*)(pooled + b * CIN + lane * 4);

    float v = zv.x * w0 + zv.y * w1 + zv.z * w2 + zv.w * w3;
    float m = pv.x * w0 + pv.y * w1 + pv.z * w2 + pv.w * w3;
#pragma unroll
    for (int off = 1; off < 64; off <<= 1) {
        v += __shfl_xor(v, off);
        m += __shfl_xor(m, off);
    }
    if (lane == 0) {
        float var = v - m * m;
        mu[gid] = m;
        rstd[gid] = rsqrtf(var + 1e-5f);
    }
}

// ---------------- K_MAIN (new): A in LDS once, B direct from global xT, fused LN+GELU ----------------
// grid = 512: xcd = bid&7, local = bid>>3; batch = xcd + 8*(local>>3); tile = local&7.
__global__ __launch_bounds__(256, 2) void k_main_xt(const unsigned short* __restrict__ xT,
                                                    const unsigned short* __restrict__ wb,
                                                    const float* __restrict__ mu,
                                                    const float* __restrict__ rstd,
                                                    const float* __restrict__ gamma,
                                                    const float* __restrict__ beta,
                                                    float* __restrict__ out) {
    __shared__ unsigned short lds_a[128 * ASTR];
    __shared__ float ls_mu[128];
    __shared__ float ls_rs[128];

    int bid = blockIdx.x;
    int xcd = bid & 7;
    int local = bid >> 3;
    int batch = xcd + 8 * (local >> 3);
    int tile = local & 7;
    int m0 = (tile & 3) * 128;
    int nh0 = (tile >> 2) * 2048;     // s-half base

    int t = threadIdx.x, lane = t & 63, w = t >> 6;
    {
        int row = t >> 1, half = t & 1;
        const unsigned short* src = wb + (size_t)(batch * COUT + m0 + row) * CIN + half * 128;
        unsigned short* dstrow = &lds_a[row * ASTR + half * 128];
#pragma unroll
        for (int j = 0; j < 16; ++j)
            *(uint4*)(dstrow + j * 8) = *(const uint4*)(src + j * 8);
    }
    if (t < 128) {
        ls_mu[t] = mu[batch * COUT + m0 + t];
        ls_rs[t] = rstd[batch * COUT + m0 + t];
    }
    __syncthreads();

    const unsigned short* xTb = xT + (size_t)batch * S_ * CIN;
    int kq = lane >> 4;

    for (int ns = 0; ns < 16; ++ns) {
        int col0 = nh0 + ns * 128 + w * 32 + (lane & 15);
        int col1 = col0 + 16;
        f32x4 acc[8][2] = {};
#pragma unroll
        for (int kk = 0; kk < 8; ++kk) {
            bf16x8 b0 = *(const bf16x8*)(xTb + (size_t)col0 * CIN + kk * 32 + kq * 8);
            bf16x8 b1 = *(const bf16x8*)(xTb + (size_t)col1 * CIN + kk * 32 + kq * 8);
#pragma unroll
            for (int mf = 0; mf < 8; ++mf) {
                bf16x8 a = *(const bf16x8*)&lds_a[(mf * 16 + (lane & 15)) * ASTR + kk * 32 + kq * 8];
                acc[mf][0] = __builtin_amdgcn_mfma_f32_16x16x32_bf16(a, b0, acc[mf][0], 0, 0, 0);
                acc[mf][1] = __builtin_amdgcn_mfma_f32_16x16x32_bf16(a, b1, acc[mf][1], 0, 0, 0);
            }
        }
        float g0 = gamma[col0], g1 = gamma[col1];
        float be0 = beta[col0], be1 = beta[col1];
#pragma unroll
        for (int mf = 0; mf < 8; ++mf) {
#pragma unroll
            for (int r = 0; r < 4; ++r) {
                int rl = mf * 16 + (lane >> 4) * 4 + r;
                float m_ = ls_mu[rl];
                float rs = ls_rs[rl];
                size_t rb = (size_t)(batch * COUT + m0 + rl) * S_;
                float z0 = (acc[mf][0][r] - m_) * rs * g0 + be0;
                float z1 = (acc[mf][1][r] - m_) * rs * g1 + be1;
                out[rb + col0] = 0.5f * z0 * (1.f + erff(z0 * 0.70710678118f));
                out[rb + col1] = 0.5f * z1 * (1.f + erff(z1 * 0.70710678118f));
            }
        }
    }
}

// ---------------- K_MAIN (fallback, R3 path): LDS-transposed B staging ----------------
#define BSTR 36
__global__ __launch_bounds__(256, 2) void k_main_fb(const float* __restrict__ x,
                                                    const unsigned short* __restrict__ wb,
                                                    const float* __restrict__ mu,
                                                    const float* __restrict__ rstd,
                                                    const float* __restrict__ gamma,
                                                    const float* __restrict__ beta,
                                                    float* __restrict__ out) {
    __shared__ unsigned short bbuf[2][128 * BSTR];
    __shared__ float ls_mu[128];
    __shared__ float ls_rs[128];

    int bid = blockIdx.x;
    int batch = (bid & 7) + 8 * (bid >> 10);
    int tile = (bid >> 3) & 127;
    int m0 = (tile & 3) * 128;
    int n0 = (tile >> 2) * 128;

    int t = threadIdx.x, lane = t & 63, w = t >> 6;
    if (t < 128) {
        ls_mu[t] = mu[batch * COUT + m0 + t];
        ls_rs[t] = rstd[batch * COUT + m0 + t];
    }
    const float* xb = x + (size_t)batch * CIN * S_;
    const unsigned short* wrow = wb + (size_t)(batch * COUT + m0 + w * 32) * CIN;

    int srow[4], sf4[4];
#pragma unroll
    for (int p = 0; p < 4; ++p) { int i = t + p * 256; srow[p] = i >> 5; sf4[p] = i & 31; }

    f32x4 acc[2][8] = {};
    float4 xr[4];
#pragma unroll
    for (int p = 0; p < 4; ++p)
        xr[p] = *(const float4*)(xb + (size_t)srow[p] * S_ + n0 + sf4[p] * 4);
    bf16x8 Ac[2], An[2];
#pragma unroll
    for (int mfi = 0; mfi < 2; ++mfi)
        Ac[mfi] = *(const bf16x8*)(wrow + (size_t)(mfi * 16 + (lane & 15)) * CIN + (lane >> 4) * 8);
#pragma unroll
    for (int p = 0; p < 4; ++p) {
        unsigned short* base = &bbuf[0][srow[p]];
        base[(sf4[p] * 4 + 0) * BSTR] = f2bf(xr[p].x);
        base[(sf4[p] * 4 + 1) * BSTR] = f2bf(xr[p].y);
        base[(sf4[p] * 4 + 2) * BSTR] = f2bf(xr[p].z);
        base[(sf4[p] * 4 + 3) * BSTR] = f2bf(xr[p].w);
    }
    __syncthreads();

#pragma unroll
    for (int step = 0; step < 8; ++step) {
        const int cur = step & 1;
        if (step < 7) {
            int k0 = (step + 1) * 32;
#pragma unroll
            for (int p = 0; p < 4; ++p)
                xr[p] = *(const float4*)(xb + (size_t)(k0 + srow[p]) * S_ + n0 + sf4[p] * 4);
#pragma unroll
            for (int mfi = 0; mfi < 2; ++mfi)
                An[mfi] = *(const bf16x8*)(wrow + (size_t)(mfi * 16 + (lane & 15)) * CIN + k0 + (lane >> 4) * 8);
        }
#pragma unroll
        for (int nf = 0; nf < 8; ++nf) {
            bf16x8 bfr = *(const bf16x8*)&bbuf[cur][(nf * 16 + (lane & 15)) * BSTR + (lane >> 4) * 8];
            acc[0][nf] = __builtin_amdgcn_mfma_f32_16x16x32_bf16(Ac[0], bfr, acc[0][nf], 0, 0, 0);
            acc[1][nf] = __builtin_amdgcn_mfma_f32_16x16x32_bf16(Ac[1], bfr, acc[1][nf], 0, 0, 0);
        }
        if (step < 7) {
#pragma unroll
            for (int p = 0; p < 4; ++p) {
                unsigned short* base = &bbuf[cur ^ 1][srow[p]];
                base[(sf4[p] * 4 + 0) * BSTR] = f2bf(xr[p].x);
                base[(sf4[p] * 4 + 1) * BSTR] = f2bf(xr[p].y);
                base[(sf4[p] * 4 + 2) * BSTR] = f2bf(xr[p].z);
                base[(sf4[p] * 4 + 3) * BSTR] = f2bf(xr[p].w);
            }
            Ac[0] = An[0]; Ac[1] = An[1];
        }
        __syncthreads();
    }

    float g[8], be[8];
#pragma unroll
    for (int nf = 0; nf < 8; ++nf) {
        int col = n0 + nf * 16 + (lane & 15);
        g[nf] = gamma[col];
        be[nf] = beta[col];
    }
#pragma unroll
    for (int mfi = 0; mfi < 2; ++mfi) {
#pragma unroll
        for (int r = 0; r < 4; ++r) {
            int rl = w * 32 + mfi * 16 + (lane >> 4) * 4 + r;
            float m_ = ls_mu[rl];
            float rs = ls_rs[rl];
            size_t rb = (size_t)(batch * COUT + m0 + rl) * S_ + n0;
#pragma unroll
            for (int nf = 0; nf < 8; ++nf) {
                float z = (acc[mfi][nf][r] - m_) * rs * g[nf] + be[nf];
                out[rb + nf * 16 + (lane & 15)] = 0.5f * z * (1.f + erff(z * 0.70710678118f));
            }
        }
    }
}

extern "C" void kernel_launch(void* const* d_in, const int* in_sizes, int n_in,
                              void* d_out, int out_size, void* d_ws, size_t ws_size,
                              hipStream_t stream) {
    const float* x      = (const float*)d_in[0];
    const float* w1     = (const float*)d_in[1];
    const float* w2     = (const float*)d_in[2];
    const float* b2     = (const float*)d_in[3];
    const float* conv_w = (const float*)d_in[4];
    // conv_b (d_in[5]) is annihilated by LayerNorm — unused.
    const float* gamma  = (const float*)d_in[6];
    const float* beta   = (const float*)d_in[7];
    float* out = (float*)d_out;

    float* pooled = (float*)d_ws;                                     // 64 KiB
    float* att    = (float*)((char*)d_ws + 65536);                    // 1 KiB
    unsigned short* wb   = (unsigned short*)((char*)d_ws + 262144);   // 16 MiB
    unsigned short* ghat = (unsigned short*)((char*)d_ws + 17039360); // 8 MiB
    float* mu   = (float*)((char*)d_ws + 25427968);                   // 128 KiB
    float* rstd = (float*)((char*)d_ws + 25559040);                   // 128 KiB
    float* ppart = (float*)((char*)d_ws + 25690112);                  // 256 KiB
    // xT: 64*4096*256*2 = 128 MiB @ offset 32 MiB (needs ws_size >= 160 MiB)
    const size_t XT_OFF = 33554432;
    const size_t XT_NEED = XT_OFF + (size_t)B_ * S_ * CIN * 2;
    bool use_xt = (ws_size >= XT_NEED);
    unsigned short* xT = use_xt ? (unsigned short*)((char*)d_ws + XT_OFF) : (unsigned short*)0;

    // scratch inside d_out (537 MB): part 64 MB @0, zbuf 33.5 MB @64MB; dead before k_main writes
    float* part = out;
    float* zbuf = (float*)((char*)d_out + 67108864);

    k_gram_part<<<256, 512, 0, stream>>>(x, part, ppart, xT);
    k_gred<<<B_, 256, 0, stream>>>(part, ppart, ghat, pooled);
    k_att<<<B_, 64, 0, stream>>>(pooled, w1, w2, b2, att);
    k_wb<<<B_ * 32, 256, 0, stream>>>(conv_w, att, wb);
    k_z<<<512, 256, 0, stream>>>(wb, ghat, zbuf);
    k_v<<<B_ * COUT / 4, 256, 0, stream>>>(zbuf, wb, pooled, mu, rstd);
    if (use_xt)
        k_main_xt<<<512, 256, 0, stream>>>(xT, wb, mu, rstd, gamma, beta, out);
    else
        k_main_fb<<<B_ * 128, 256, 0, stream>>>(x, wb, mu, rstd, gamma, beta, out);
}

// Round 5
// 509.031 us; speedup vs baseline: 1.3131x; 1.3131x over previous
//
#include <hip/hip_runtime.h>
#include <hip/hip_bf16.h>

#define B_   64
#define CIN  256
#define COUT 512
#define S_   4096
#define HID  64
#define KEXP 4

typedef float f32x4 __attribute__((ext_vector_type(4)));
typedef short bf16x8 __attribute__((ext_vector_type(8)));

static __device__ __forceinline__ unsigned short f2bf(float f) {
    union { float f; unsigned u; } c; c.f = f;
    unsigned r = c.u + 0x7FFFu + ((c.u >> 16) & 1u);
    return (unsigned short)(r >> 16);
}
static __device__ __forceinline__ float bf2f(unsigned short u) {
    union { unsigned u; float f; } c; c.u = ((unsigned)u) << 16;
    return c.f;
}

// ---------------- K_GRAM_PART: partial Gram (fp32) + partial pooled + xF (frag-packed bf16) ----
// grid = 256: b = bid&63, sc = bid>>6 (s-chunk of 1024). 512 threads (8 waves).
// xF layout per batch: [st = s/16][kb = k/32] chunks of 512 shorts; within chunk lane l owns
// shorts l*8..l*8+8 = (col = st*16 + (l&15), k = kb*32 + (l>>4)*8 + j). Exact MFMA B-frag order.
#define GSTR 68   // shorts per LDS row (136B)
__global__ __launch_bounds__(512, 2) void k_gram_part(const float* __restrict__ x,
                                                      float* __restrict__ part,
                                                      float* __restrict__ ppart,
                                                      unsigned short* __restrict__ xF) {
    __shared__ unsigned short lds[256 * GSTR];   // 34816 B
    int bid = blockIdx.x;
    int b = bid & 63, sc = bid >> 6;
    int t = threadIdx.x, lane = t & 63, wv = t >> 6;
    int wr = wv >> 1, wc = wv & 1;               // wave tile: rows wr*64.., cols wc*128..
    const float* xb = x + (size_t)b * CIN * S_;
    unsigned short* xFb = xF + (size_t)b * S_ * CIN;

    f32x4 acc[4][8] = {};
    float psum[8] = {0.f, 0.f, 0.f, 0.f, 0.f, 0.f, 0.f, 0.f};

    for (int step = 0; step < 16; ++step) {
        int s0 = sc * 1024 + step * 64;
        __syncthreads();
#pragma unroll
        for (int p = 0; p < 8; ++p) {
            int i = t + p * 512;
            int row = i >> 4, f4 = i & 15;
            float4 v = *(const float4*)(xb + (size_t)row * S_ + s0 + f4 * 4);
            psum[p] += v.x + v.y + v.z + v.w;
            unsigned short u[4] = {f2bf(v.x), f2bf(v.y), f2bf(v.z), f2bf(v.w)};
            *(uint2*)&lds[row * GSTR + f4 * 4] = *(const uint2*)u;
        }
        __syncthreads();
        // ---- xF write: frag-packed, 1KB-contiguous per wave-chunk ----
        {
#pragma unroll
            for (int it = 0; it < 4; ++it) {
                int slot = t + it * 512;
                int chunk = slot >> 6;           // 0..31 = st_l*8 + kb
                int st_l = chunk >> 3, kb = chunk & 7;
                int l = slot & 63;
                unsigned short tmp[8];
#pragma unroll
                for (int j = 0; j < 8; ++j)
                    tmp[j] = lds[(kb * 32 + (l >> 4) * 8 + j) * GSTR + st_l * 16 + (l & 15)];
                *(uint4*)(xFb + ((size_t)((s0 >> 4) + st_l) * 8 + kb) * 512 + l * 8) = *(const uint4*)tmp;
            }
        }
        // ---- Gram MFMA ----
#pragma unroll
        for (int kk = 0; kk < 2; ++kk) {
            bf16x8 bfr[8];
#pragma unroll
            for (int nf = 0; nf < 8; ++nf)
                bfr[nf] = *(const bf16x8*)&lds[(wc * 128 + nf * 16 + (lane & 15)) * GSTR + kk * 32 + (lane >> 4) * 8];
#pragma unroll
            for (int mfi = 0; mfi < 4; ++mfi) {
                bf16x8 afr = *(const bf16x8*)&lds[(wr * 64 + mfi * 16 + (lane & 15)) * GSTR + kk * 32 + (lane >> 4) * 8];
#pragma unroll
                for (int nf = 0; nf < 8; ++nf)
                    acc[mfi][nf] = __builtin_amdgcn_mfma_f32_16x16x32_bf16(afr, bfr[nf], acc[mfi][nf], 0, 0, 0);
            }
        }
    }
#pragma unroll
    for (int p = 0; p < 8; ++p) {
        float s = psum[p];
        s += __shfl_xor(s, 1); s += __shfl_xor(s, 2);
        s += __shfl_xor(s, 4); s += __shfl_xor(s, 8);
        if ((t & 15) == 0) ppart[((size_t)sc * 64 + b) * 256 + ((t + p * 512) >> 4)] = s;
    }
    float* pb = part + ((size_t)sc * 64 + b) * 65536;
#pragma unroll
    for (int mfi = 0; mfi < 4; ++mfi) {
#pragma unroll
        for (int r = 0; r < 4; ++r) {
            int row = wr * 64 + mfi * 16 + (lane >> 4) * 4 + r;
#pragma unroll
            for (int nf = 0; nf < 8; ++nf)
                pb[row * 256 + wc * 128 + nf * 16 + (lane & 15)] = acc[mfi][nf][r];
        }
    }
}

// ---------------- K_GRED: reduce 4 partials -> ghat bf16, pooled ----------------
__global__ __launch_bounds__(256) void k_gred(const float* __restrict__ part,
                                              const float* __restrict__ ppart,
                                              unsigned short* __restrict__ ghat,
                                              float* __restrict__ pooled) {
    int b = blockIdx.x, t = threadIdx.x;
    const size_t bo = (size_t)b * 65536;
    const size_t scs = (size_t)64 * 65536;
    const float inv = 1.f / S_;
    for (int it = 0; it < 64; ++it) {
        size_t i = (size_t)(it * 256 + t) * 4;
        float4 a0 = *(const float4*)(part + bo + i);
        float4 a1 = *(const float4*)(part + scs + bo + i);
        float4 a2 = *(const float4*)(part + 2 * scs + bo + i);
        float4 a3 = *(const float4*)(part + 3 * scs + bo + i);
        unsigned short u[4] = {f2bf((a0.x + a1.x + a2.x + a3.x) * inv),
                               f2bf((a0.y + a1.y + a2.y + a3.y) * inv),
                               f2bf((a0.z + a1.z + a2.z + a3.z) * inv),
                               f2bf((a0.w + a1.w + a2.w + a3.w) * inv)};
        *(uint2*)&ghat[bo + i] = *(const uint2*)u;
    }
    float p = ppart[(size_t)b * 256 + t] + ppart[(size_t)(64 + b) * 256 + t]
            + ppart[(size_t)(128 + b) * 256 + t] + ppart[(size_t)(192 + b) * 256 + t];
    pooled[b * 256 + t] = p * inv;
}

// ---------------- K2: attention weights ----------------
__global__ __launch_bounds__(64) void k_att(const float* __restrict__ pooled,
                                            const float* __restrict__ w1,
                                            const float* __restrict__ w2,
                                            const float* __restrict__ b2,
                                            float* __restrict__ att_out) {
    int b = blockIdx.x, t = threadIdx.x;
    __shared__ float pl[CIN];
    __shared__ float hl[HID];
    __shared__ float satt[KEXP];
    for (int j = t; j < CIN; j += 64) pl[j] = pooled[b * CIN + j];
    __syncthreads();
    float acc = 0.f;
    const float* w1r = w1 + t * CIN;
#pragma unroll 4
    for (int c = 0; c < CIN; c += 4) {
        float4 w = *(const float4*)(w1r + c);
        acc += w.x * pl[c] + w.y * pl[c + 1] + w.z * pl[c + 2] + w.w * pl[c + 3];
    }
    hl[t] = fmaxf(acc, 0.f);
    __syncthreads();
    if (t < KEXP) {
        float a = 0.f;
        for (int j = 0; j < HID; ++j) a += hl[j] * w2[t * HID + j];
        satt[t] = (a + b2[t]) * (1.0f / 30.0f);
    }
    __syncthreads();
    if (t == 0) {
        float m = fmaxf(fmaxf(satt[0], satt[1]), fmaxf(satt[2], satt[3]));
        float e0 = expf(satt[0] - m), e1 = expf(satt[1] - m);
        float e2 = expf(satt[2] - m), e3 = expf(satt[3] - m);
        float inv = 1.f / (e0 + e1 + e2 + e3);
        att_out[b * KEXP + 0] = e0 * inv;
        att_out[b * KEXP + 1] = e1 * inv;
        att_out[b * KEXP + 2] = e2 * inv;
        att_out[b * KEXP + 3] = e3 * inv;
    }
}

// ---------------- K2b: Wb[b] = sum_k att[b,k] conv_w[k]  (bf16 to ws) ----------------
__global__ __launch_bounds__(256) void k_wb(const float* __restrict__ conv_w,
                                            const float* __restrict__ att,
                                            unsigned short* __restrict__ wb) {
    int bid = blockIdx.x;
    int b = bid >> 5, o0 = (bid & 31) * 16;
    int t = threadIdx.x;
    int o = o0 + (t >> 4);
    int i0 = (t & 15) * 16;
    float ak[KEXP];
#pragma unroll
    for (int k = 0; k < KEXP; ++k) ak[k] = att[b * KEXP + k];
    float acc[16];
#pragma unroll
    for (int j = 0; j < 16; ++j) acc[j] = 0.f;
#pragma unroll
    for (int k = 0; k < KEXP; ++k) {
        const float* src = conv_w + ((size_t)(k * COUT + o)) * CIN + i0;
#pragma unroll
        for (int j4 = 0; j4 < 4; ++j4) {
            float4 v = *(const float4*)(src + j4 * 4);
            acc[j4 * 4 + 0] += ak[k] * v.x;
            acc[j4 * 4 + 1] += ak[k] * v.y;
            acc[j4 * 4 + 2] += ak[k] * v.z;
            acc[j4 * 4 + 3] += ak[k] * v.w;
        }
    }
    unsigned short us[16];
#pragma unroll
    for (int j = 0; j < 16; ++j) us[j] = f2bf(acc[j]);
    unsigned short* dst = wb + (size_t)(b * COUT + o) * CIN + i0;
    *(uint4*)(dst) = *(const uint4*)(us);
    *(uint4*)(dst + 8) = *(const uint4*)(us + 8);
}

#define ASTR 264

// ---------------- K_Z: Z[b] = Wb[b] @ Ghat[b] ----------------
__global__ __launch_bounds__(256, 2) void k_z(const unsigned short* __restrict__ wb,
                                              const unsigned short* __restrict__ ghat,
                                              float* __restrict__ zout) {
    __shared__ unsigned short lds_a[128 * ASTR];
    int bid = blockIdx.x;
    int b = bid & 63;
    int tile = bid >> 6;               // 0..7
    int m0 = (tile & 3) * 128, n0 = (tile >> 2) * 128;
    int t = threadIdx.x;
    {
        int row = t >> 1, half = t & 1;
        const unsigned short* src = wb + (size_t)(b * COUT + m0 + row) * CIN + half * 128;
        unsigned short* dstrow = &lds_a[row * ASTR + half * 128];
#pragma unroll
        for (int j = 0; j < 16; ++j)
            *(uint4*)(dstrow + j * 8) = *(const uint4*)(src + j * 8);
    }
    __syncthreads();

    int lane = t & 63;
    int wid = t >> 6;
    int arow = lane & 15;
    int kq = lane >> 4;
    int col0 = n0 + wid * 32 + (lane & 15);
    int col1 = col0 + 16;
    const unsigned short* gb = ghat + (size_t)b * 256 * 256;

    f32x4 acc[8][2] = {};
#pragma unroll
    for (int kk = 0; kk < 8; ++kk) {
        bf16x8 b0 = *(const bf16x8*)(gb + (size_t)col0 * 256 + kk * 32 + kq * 8);
        bf16x8 b1 = *(const bf16x8*)(gb + (size_t)col1 * 256 + kk * 32 + kq * 8);
#pragma unroll
        for (int mf = 0; mf < 8; ++mf) {
            int row = mf * 16 + arow;
            bf16x8 a = *(const bf16x8*)&lds_a[row * ASTR + kk * 32 + kq * 8];
            acc[mf][0] = __builtin_amdgcn_mfma_f32_16x16x32_bf16(a, b0, acc[mf][0], 0, 0, 0);
            acc[mf][1] = __builtin_amdgcn_mfma_f32_16x16x32_bf16(a, b1, acc[mf][1], 0, 0, 0);
        }
    }
#pragma unroll
    for (int mf = 0; mf < 8; ++mf) {
#pragma unroll
        for (int r = 0; r < 4; ++r) {
            int row = m0 + mf * 16 + (lane >> 4) * 4 + r;
            size_t rb = ((size_t)b * COUT + row) * 256;
#pragma unroll
            for (int nf = 0; nf < 2; ++nf) {
                int col = n0 + wid * 32 + nf * 16 + (lane & 15);
                zout[rb + col] = acc[mf][nf][r];
            }
        }
    }
}

// ---------------- K_V: mu/rstd per (b,o) ----------------
__global__ __launch_bounds__(256) void k_v(const float* __restrict__ z,
                                           const unsigned short* __restrict__ wb,
                                           const float* __restrict__ pooled,
                                           float* __restrict__ mu,
                                           float* __restrict__ rstd) {
    int gid = blockIdx.x * 4 + (threadIdx.x >> 6);   // b*512 + o
    int lane = threadIdx.x & 63;
    int b = gid >> 9;
    const float* zr = z + (size_t)gid * 256;
    const unsigned short* wr = wb + (size_t)gid * 256;

    float4 zv = *(const float4*)(zr + lane * 4);
    ushort4 wu = *(const ushort4*)(wr + lane * 4);
    float w0 = bf2f(wu.x), w1 = bf2f(wu.y), w2 = bf2f(wu.z), w3 = bf2f(wu.w);
    float4 pv = *(const float4*)(pooled + b * CIN + lane * 4);

    float v = zv.x * w0 + zv.y * w1 + zv.z * w2 + zv.w * w3;
    float m = pv.x * w0 + pv.y * w1 + pv.z * w2 + pv.w * w3;
#pragma unroll
    for (int off = 1; off < 64; off <<= 1) {
        v += __shfl_xor(v, off);
        m += __shfl_xor(m, off);
    }
    if (lane == 0) {
        float var = v - m * m;
        mu[gid] = m;
        rstd[gid] = rsqrtf(var + 1e-5f);
    }
}

// ---------------- K_MAIN5: BM=256, A frag-packed in LDS, B streamed frag-packed, LN+GELU ----
// grid = 256 (1 block/CU): batch = (bid&7)*8 + ((bid>>3)&7); m0 = ((bid>>6)&1)*256; sh = bid>>7.
// 512 threads = 8 waves: mgrp = w&3 (64 rows), cb = w>>2 (16-col block within 32-col sub).
__global__ __launch_bounds__(512, 1) void k_main5(const unsigned short* __restrict__ xF,
                                                  const unsigned short* __restrict__ wb,
                                                  const float* __restrict__ mu,
                                                  const float* __restrict__ rstd,
                                                  const float* __restrict__ gamma,
                                                  const float* __restrict__ beta,
                                                  float* __restrict__ out) {
    __shared__ unsigned short lds_a[256 * 256];   // 128 KiB, frag-packed A
    __shared__ unsigned short bbuf[8192];         // 16 KiB, one 32-col sub of B

    int bid = blockIdx.x;
    int batch = (bid & 7) * 8 + ((bid >> 3) & 7);
    int m0 = ((bid >> 6) & 1) * 256;
    int sh = (bid >> 7) & 1;

    int t = threadIdx.x, lane = t & 63;
    int w = t >> 6;
    int mgrp = w & 3, cb = w >> 2;
    int lm = lane & 15, lk = lane >> 4;

    // ---- stage A frag-packed: chunk(mfblk,kk) -> lane l owns 16B ----
    const unsigned short* wbb = wb + (size_t)(batch * COUT + m0) * CIN;
#pragma unroll
    for (int it = 0; it < 16; ++it) {
        int i = it * 512 + t;
        int chunk = i >> 6, l = i & 63;
        int row = (chunk >> 3) * 16 + (l & 15);
        int kk = chunk & 7;
        uint4 v = *(const uint4*)(wbb + (size_t)row * CIN + kk * 32 + (l >> 4) * 8);
        *(uint4*)&lds_a[(size_t)i * 8] = v;
    }

    // ---- preload mu/rstd for this lane's 16 output rows ----
    float mu_r[16], rs_r[16];
#pragma unroll
    for (int mf = 0; mf < 4; ++mf)
#pragma unroll
        for (int rr = 0; rr < 4; ++rr) {
            int row = batch * COUT + m0 + mgrp * 64 + mf * 16 + lk * 4 + rr;
            mu_r[mf * 4 + rr] = mu[row];
            rs_r[mf * 4 + rr] = rstd[row];
        }

    const unsigned short* xFb = xF + (size_t)batch * S_ * CIN;
    // ---- stage B sub 0 ----
    {
        size_t sb = (size_t)(sh * 128) * 4096;
        uint4 a = *(const uint4*)(xFb + sb + (size_t)t * 8);
        uint4 b = *(const uint4*)(xFb + sb + (size_t)(512 + t) * 8);
        *(uint4*)&bbuf[t * 8] = a;
        *(uint4*)&bbuf[(512 + t) * 8] = b;
    }
    __syncthreads();

    f32x4 acc[4] = {};
    for (int s = 0; s < 64; ++s) {
        // T14: issue next sub's global loads before compute
        uint4 xa, xb2;
        if (s < 63) {
            size_t sb = (size_t)(sh * 128 + (s + 1) * 2) * 4096;
            xa  = *(const uint4*)(xFb + sb + (size_t)t * 8);
            xb2 = *(const uint4*)(xFb + sb + (size_t)(512 + t) * 8);
        }
        // ---- compute: 32 MFMA per wave ----
#pragma unroll
        for (int kk = 0; kk < 8; ++kk) {
            bf16x8 bfr = *(const bf16x8*)&bbuf[cb * 4096 + kk * 512 + lane * 8];
#pragma unroll
            for (int mf = 0; mf < 4; ++mf) {
                bf16x8 afr = *(const bf16x8*)&lds_a[(size_t)(((mgrp * 4 + mf) * 8 + kk) * 512) + lane * 8];
                acc[mf] = __builtin_amdgcn_mfma_f32_16x16x32_bf16(afr, bfr, acc[mf], 0, 0, 0);
            }
        }
        // ---- epilogue: LN + exact GELU for this sub's 16 values/lane ----
        int col = sh * 2048 + s * 32 + cb * 16 + lm;
        float g = gamma[col], be = beta[col];
#pragma unroll
        for (int mf = 0; mf < 4; ++mf) {
#pragma unroll
            for (int rr = 0; rr < 4; ++rr) {
                float z = (acc[mf][rr] - mu_r[mf * 4 + rr]) * rs_r[mf * 4 + rr] * g + be;
                int row = m0 + mgrp * 64 + mf * 16 + lk * 4 + rr;
                out[(size_t)(batch * COUT + row) * S_ + col] =
                    0.5f * z * (1.f + erff(z * 0.70710678118f));
            }
            acc[mf] = (f32x4){0.f, 0.f, 0.f, 0.f};
        }
        __syncthreads();                 // all reads of bbuf done
        if (s < 63) {
            *(uint4*)&bbuf[t * 8] = xa;
            *(uint4*)&bbuf[(512 + t) * 8] = xb2;
        }
        __syncthreads();                 // bbuf refilled
    }
}

extern "C" void kernel_launch(void* const* d_in, const int* in_sizes, int n_in,
                              void* d_out, int out_size, void* d_ws, size_t ws_size,
                              hipStream_t stream) {
    const float* x      = (const float*)d_in[0];
    const float* w1     = (const float*)d_in[1];
    const float* w2     = (const float*)d_in[2];
    const float* b2     = (const float*)d_in[3];
    const float* conv_w = (const float*)d_in[4];
    // conv_b (d_in[5]) is annihilated by LayerNorm — unused.
    const float* gamma  = (const float*)d_in[6];
    const float* beta   = (const float*)d_in[7];
    float* out = (float*)d_out;

    float* pooled = (float*)d_ws;                                     // 64 KiB
    float* att    = (float*)((char*)d_ws + 65536);                    // 1 KiB
    unsigned short* wb   = (unsigned short*)((char*)d_ws + 262144);   // 16 MiB
    unsigned short* ghat = (unsigned short*)((char*)d_ws + 17039360); // 8 MiB
    float* mu   = (float*)((char*)d_ws + 25427968);                   // 128 KiB
    float* rstd = (float*)((char*)d_ws + 25559040);                   // 128 KiB
    float* ppart = (float*)((char*)d_ws + 25690112);                  // 256 KiB
    // xF: 128 MiB @ 32 MiB (ws_size >= 160 MiB proven in R4 — the xt path ran)
    unsigned short* xF = (unsigned short*)((char*)d_ws + 33554432);

    // scratch inside d_out (537 MB): part 64 MB @0, zbuf 33.5 MB @64MB; dead before k_main5 writes
    float* part = out;
    float* zbuf = (float*)((char*)d_out + 67108864);

    k_gram_part<<<256, 512, 0, stream>>>(x, part, ppart, xF);
    k_gred<<<B_, 256, 0, stream>>>(part, ppart, ghat, pooled);
    k_att<<<B_, 64, 0, stream>>>(pooled, w1, w2, b2, att);
    k_wb<<<B_ * 32, 256, 0, stream>>>(conv_w, att, wb);
    k_z<<<512, 256, 0, stream>>>(wb, ghat, zbuf);
    k_v<<<B_ * COUT / 4, 256, 0, stream>>>(zbuf, wb, pooled, mu, rstd);
    k_main5<<<256, 512, 0, stream>>>(xF, wb, mu, rstd, gamma, beta, out);
}